// Round 2
// baseline (309.878 us; speedup 1.0000x reference)
//
#include <hip/hip_runtime.h>

// PositionId gather: out[t, :] = buffer[t - offsets[seg(t)], :]
// buffer: [8192, 1024] fp32, offsets: [17] int32, out: [65536, 1024] fp32.
//
// v2b: 32 rows per block, 8-deep unrolled row loop (8 dwordx4 loads in flight
// per lane), offsets staged in LDS once per block, monotone segment advance
// (uniform per block), non-temporal stores for the streaming output.
// Uses a native ext_vector float4 (v4f) so __builtin_nontemporal_store accepts it.

#define D_MODEL 1024
#define V4 (D_MODEL / 4)        // 256 float4 per row; one thread per float4 col
#define ROWS_PER_BLOCK 32
#define UNROLL 8
#define MAX_OFF 64              // generous bound for offsets in LDS

typedef float v4f __attribute__((ext_vector_type(4)));

__global__ __launch_bounds__(256, 8) void positionid_gather(
    const v4f* __restrict__ buf,         // [MAX_SEQLEN, 256] as v4f
    const int* __restrict__ offsets,     // [n_off]
    int n_off,                           // BATCH+1 (17)
    v4f*       __restrict__ out,         // [T, 256] as v4f
    int T)
{
    __shared__ int soff[MAX_OFF];
    const int tid = threadIdx.x;
    if (tid < n_off) soff[tid] = offsets[tid];
    __syncthreads();

    const int t0 = blockIdx.x * ROWS_PER_BLOCK;
    if (t0 >= T) return;

    // Advance to t0's segment: seg = max i such that soff[i] <= t.
    // t0 is block-uniform -> uniform loop over LDS broadcasts.
    int seg = 0;
    while (seg + 2 < n_off && soff[seg + 1] <= t0) ++seg;

    if (t0 + ROWS_PER_BLOCK <= T) {
        // Fast path: full tile, branch-free unrolled copy.
        for (int r = 0; r < ROWS_PER_BLOCK; r += UNROLL) {
            int pos[UNROLL];
            #pragma unroll
            for (int k = 0; k < UNROLL; ++k) {
                const int t = t0 + r + k;
                while (seg + 2 < n_off && soff[seg + 1] <= t) ++seg;
                pos[k] = t - soff[seg];
            }
            v4f v[UNROLL];
            #pragma unroll
            for (int k = 0; k < UNROLL; ++k)
                v[k] = buf[(size_t)pos[k] * V4 + tid];
            #pragma unroll
            for (int k = 0; k < UNROLL; ++k)
                __builtin_nontemporal_store(
                    v[k], &out[(size_t)(t0 + r + k) * V4 + tid]);
        }
    } else {
        // Tail tile: per-row guard.
        for (int r = 0; r < ROWS_PER_BLOCK; ++r) {
            const int t = t0 + r;
            if (t >= T) break;
            while (seg + 2 < n_off && soff[seg + 1] <= t) ++seg;
            const int pos = t - soff[seg];
            v4f v = buf[(size_t)pos * V4 + tid];
            __builtin_nontemporal_store(v, &out[(size_t)t * V4 + tid]);
        }
    }
}

extern "C" void kernel_launch(void* const* d_in, const int* in_sizes, int n_in,
                              void* d_out, int out_size, void* d_ws, size_t ws_size,
                              hipStream_t stream) {
    const v4f* buf     = (const v4f*)d_in[0];
    const int* offsets = (const int*)d_in[1];
    const int  n_off   = in_sizes[1];          // 17
    v4f*       out     = (v4f*)d_out;

    const int T = out_size / D_MODEL;          // 65536 token rows

    const int nblocks = (T + ROWS_PER_BLOCK - 1) / ROWS_PER_BLOCK;  // 2048
    positionid_gather<<<dim3(nblocks), dim3(256), 0, stream>>>(
        buf, offsets, n_off, out, T);
}

// Round 4
// 294.964 us; speedup vs baseline: 1.0506x; 1.0506x over previous
//
#include <hip/hip_runtime.h>

// PositionId gather, position-major: for each buffer row p, broadcast it to
// every segment i with p < L_i:  out[offsets[i] + p, :] = buffer[p, :].
// This reads each buffer row from HBM exactly ONCE (32 MB total) instead of
// once per segment (~268 MB when token-major order defeats L2/L3 reuse),
// while writes (268 MB) are mandatory and stay wave-coalesced.
//
// buffer: [8192, 1024] fp32, offsets: [17] int32, out: [65536, 1024] fp32.

#define D_MODEL 1024
#define V4 (D_MODEL / 4)        // 256 float4 per row; one thread per float4 col
#define RPOS 4                  // buffer rows (positions) per block
#define MAX_OFF 64              // generous bound for offsets in LDS

typedef float v4f __attribute__((ext_vector_type(4)));

__global__ __launch_bounds__(256, 8) void positionid_scatter(
    const v4f* __restrict__ buf,         // [buf_rows, 256] as v4f
    const int* __restrict__ offsets,     // [n_off]
    int n_off,                           // BATCH+1 (17)
    v4f*       __restrict__ out,         // [T, 256] as v4f
    int buf_rows)
{
    __shared__ int soff[MAX_OFF];
    const int tid = threadIdx.x;
    if (tid < n_off) soff[tid] = offsets[tid];
    __syncthreads();

    const int p0 = blockIdx.x * RPOS;
    if (p0 >= buf_rows) return;

    // Load this block's buffer rows once (registers), guarded for the tail.
    v4f v[RPOS];
    #pragma unroll
    for (int k = 0; k < RPOS; ++k) {
        const int p = p0 + k;
        v[k] = buf[(size_t)(p < buf_rows ? p : 0) * V4 + tid];
    }

    // Broadcast to every segment that contains position p.
    // (p, len) are block-uniform -> scalar branch, zero divergence.
    const int nseg = n_off - 1;
    for (int i = 0; i < nseg; ++i) {
        const int base = soff[i];
        const int len  = soff[i + 1] - base;
        #pragma unroll
        for (int k = 0; k < RPOS; ++k) {
            const int p = p0 + k;
            if (p < len)   // implies p < buf_rows since len <= buf_rows
                __builtin_nontemporal_store(
                    v[k], &out[(size_t)(base + p) * V4 + tid]);
        }
    }
}

extern "C" void kernel_launch(void* const* d_in, const int* in_sizes, int n_in,
                              void* d_out, int out_size, void* d_ws, size_t ws_size,
                              hipStream_t stream) {
    const v4f* buf     = (const v4f*)d_in[0];
    const int* offsets = (const int*)d_in[1];
    const int  n_off   = in_sizes[1];              // 17 (element count)
    v4f*       out     = (v4f*)d_out;

    const int buf_rows = in_sizes[0] / D_MODEL;    // 8192

    const int nblocks = (buf_rows + RPOS - 1) / RPOS;   // 2048
    positionid_scatter<<<dim3(nblocks), dim3(256), 0, stream>>>(
        buf, offsets, n_off, out, buf_rows);
}

// Round 5
// 293.300 us; speedup vs baseline: 1.0565x; 1.0057x over previous
//
#include <hip/hip_runtime.h>

// PositionId, position-major scatter with STRIDED position assignment:
// block b owns positions p_k = b + k*PSTRIDE (k = 0..RPOS-1), so every block
// issues a near-equal number of stores (~Sum_k #{i: L_i > p_k} is ~constant
// in b), instead of the 8:1 block imbalance of the contiguous mapping.
// Each buffer row is still read from HBM exactly once (32 MB total); writes
// (268 MB, mandatory) stay wave-coalesced non-temporal.
//
// buffer: [8192, 1024] fp32, offsets: [17] int32, out: [65536, 1024] fp32.

#define D_MODEL 1024
#define V4 (D_MODEL / 4)        // 256 float4 per row; one thread per float4 col
#define RPOS 8                  // positions per block, strided across the range
#define MAX_OFF 64              // generous bound for offsets in LDS

typedef float v4f __attribute__((ext_vector_type(4)));

__global__ __launch_bounds__(256, 8) void positionid_scatter(
    const v4f* __restrict__ buf,         // [buf_rows, 256] as v4f
    const int* __restrict__ offsets,     // [n_off]
    int n_off,                           // BATCH+1 (17)
    v4f*       __restrict__ out,         // [T, 256] as v4f
    int buf_rows,
    int pstride)                         // ceil(buf_rows / RPOS)
{
    __shared__ int soff[MAX_OFF];
    const int tid = threadIdx.x;
    if (tid < n_off) soff[tid] = offsets[tid];
    __syncthreads();

    const int b = blockIdx.x;            // b in [0, pstride)

    // Load this block's strided buffer rows once (RPOS independent loads in
    // flight). p_k = b + k*pstride; guard the tail (p_k >= buf_rows unused).
    int  p[RPOS];
    v4f  v[RPOS];
    #pragma unroll
    for (int k = 0; k < RPOS; ++k) {
        p[k] = b + k * pstride;
        v[k] = buf[(size_t)(p[k] < buf_rows ? p[k] : 0) * V4 + tid];
    }

    // Broadcast each position to every segment containing it.
    // (p, len) are block-uniform -> scalar predicates, zero divergence.
    const int nseg = n_off - 1;
    for (int i = 0; i < nseg; ++i) {
        const int base = soff[i];
        const int len  = soff[i + 1] - base;   // len <= buf_rows
        #pragma unroll
        for (int k = 0; k < RPOS; ++k) {
            if (p[k] < len)                    // implies p[k] < buf_rows
                __builtin_nontemporal_store(
                    v[k], &out[(size_t)(base + p[k]) * V4 + tid]);
        }
    }
}

extern "C" void kernel_launch(void* const* d_in, const int* in_sizes, int n_in,
                              void* d_out, int out_size, void* d_ws, size_t ws_size,
                              hipStream_t stream) {
    const v4f* buf     = (const v4f*)d_in[0];
    const int* offsets = (const int*)d_in[1];
    const int  n_off   = in_sizes[1];              // 17 (element count)
    v4f*       out     = (v4f*)d_out;

    const int buf_rows = in_sizes[0] / D_MODEL;    // 8192
    const int pstride  = (buf_rows + RPOS - 1) / RPOS;   // 1024

    positionid_scatter<<<dim3(pstride), dim3(256), 0, stream>>>(
        buf, offsets, n_off, out, buf_rows, pstride);
}